// Round 5
// baseline (4413.626 us; speedup 1.0000x reference)
//
#include <hip/hip_runtime.h>
#include <cstdint>

// ---------------------------------------------------------------------------
// SparseAttention — R5: attn kernel restructured for operand reuse.
//  - QK^T: wave owns a 256-key slice, computes ALL 8 q-rows per K element
//    (8x less LDS read traffic); K staged via global_load_lds double-buffer
//    with counted vmcnt (conflict-free linear layout).
//  - f64 score transpose through LDS (2 halves, same type, barrier-fenced)
//    restores the R3/R4-verified per-wave-row layout; selection/softmax code
//    is verbatim R4 => bit-identical selection (absmax must stay 2.563e-3).
//  - PV / qkv / out-proj unchanged from R4.
// ---------------------------------------------------------------------------

#define BB 2
#define NN 2048
#define CC 1024
#define HH 16
#define HD 64
#define KSP 204

#define LAS(p) ((__attribute__((address_space(3))) void*)(uintptr_t)(p))
#define GAS(p) ((const __attribute__((address_space(1))) void*)(uintptr_t)(p))

__device__ __forceinline__ unsigned long long mono64(double s) {
  long long bb = __double_as_longlong(s);
  return (unsigned long long)bb ^
         ((bb < 0) ? 0xFFFFFFFFFFFFFFFFull : 0x8000000000000000ull);
}

// ---------------------------------------------------------------------------
// Kernel 1: qkv = x @ w_qkv + b_qkv in fp64. 64x64 tile, 4x4 micro. (R4)
// ---------------------------------------------------------------------------
__global__ __launch_bounds__(256) void qkv_gemm_f64(
    const float* __restrict__ x, const float* __restrict__ w,
    const float* __restrict__ bqkv, double* __restrict__ Qd,
    double* __restrict__ Kd, float* __restrict__ Vf) {
  __shared__ double As[16][64];  // [k][m]
  __shared__ double Bs[16][64];  // [k][n]
  const int tid = threadIdx.x;
  const int tx = tid & 15, ty = tid >> 4;
  const int colbase = blockIdx.x * 64, rowbase = blockIdx.y * 64;

  double acc[4][4] = {};

  const int sr = tid >> 2, sc = (tid & 3) * 4;
  const int bk = tid >> 4, bn = (tid & 15) * 4;

  for (int kt = 0; kt < 64; ++kt) {
    const int k0 = kt * 16;
    const float4 av = *(const float4*)(x + (size_t)(rowbase + sr) * 1024 + k0 + sc);
    const float4 bv = *(const float4*)(w + (size_t)(k0 + bk) * 3072 + colbase + bn);
    __syncthreads();
    As[sc + 0][sr] = (double)av.x;
    As[sc + 1][sr] = (double)av.y;
    As[sc + 2][sr] = (double)av.z;
    As[sc + 3][sr] = (double)av.w;
    Bs[bk][bn + 0] = (double)bv.x;
    Bs[bk][bn + 1] = (double)bv.y;
    Bs[bk][bn + 2] = (double)bv.z;
    Bs[bk][bn + 3] = (double)bv.w;
    __syncthreads();
#pragma unroll
    for (int k = 0; k < 16; ++k) {
      double a[4], b[4];
#pragma unroll
      for (int i = 0; i < 4; ++i) a[i] = As[k][ty + 16 * i];
#pragma unroll
      for (int j = 0; j < 4; ++j) b[j] = Bs[k][tx + 16 * j];
#pragma unroll
      for (int i = 0; i < 4; ++i)
#pragma unroll
        for (int j = 0; j < 4; ++j) acc[i][j] = fma(a[i], b[j], acc[i][j]);
    }
  }

  const int region = colbase >> 10;  // 0=Q 1=K 2=V
#pragma unroll
  for (int j = 0; j < 4; ++j) {
    const int col = colbase + tx + 16 * j;
    const double bias = (double)bqkv[col];
    const int h = (col & 1023) >> 6, d = col & 63;
#pragma unroll
    for (int i = 0; i < 4; ++i) {
      const int row = rowbase + ty + 16 * i;
      const int b = row >> 11, n = row & 2047;
      const size_t o = ((size_t)((b * HH + h) * HD + d)) * NN + n;
      const double v = acc[i][j] + bias;
      if (region == 0)
        Qd[o] = v * 0.125;
      else if (region == 1)
        Kd[o] = v;
      else
        Vf[o] = (float)v;
    }
  }
}

// ---------------------------------------------------------------------------
// Kernel 2: fused sparse attention (R5 restructure; selection semantics
// bit-identical to R3/R4).
// Block 512 thr = 8 waves; 8 q-rows per block.
// QK phase: wave w owns keys [256w, 256w+256), computes all 8 rows.
// Then f64 transpose via LDS -> wave w owns row w (key = lane+64i), and the
// R4-verified selection/softmax runs verbatim. PV identical to R4.
// ---------------------------------------------------------------------------
__global__ __launch_bounds__(512) void attn_exact(
    const double* __restrict__ Qd, const double* __restrict__ Kd,
    const float* __restrict__ Vf, float* __restrict__ attnv) {
  __shared__ double KS[8192];          // 64KB: K dbuf (2 x 2 d-rows x 2048) / Sf
  __shared__ _Float16 Pf[8][2048];     // 32KB
  __shared__ double Qrow[8][64];       // 4KB
  __shared__ float Zrow[8];

  const int tid = threadIdx.x;
  const int lane = tid & 63;
  const int w = tid >> 6;
  const int bh = (int)blockIdx.x >> 8;
  const int n0 = ((int)blockIdx.x & 255) * 8;

  Qrow[w][lane] = Qd[((size_t)bh * HD + lane) * NN + n0 + w];

  const double* Kbh = Kd + (size_t)bh * HD * NN;

  // stage s covers d-rows {2s, 2s+1}; 32 segments of 1024B; wave w does 4.
#define ISSUE_STAGE(s)                                                        \
  {                                                                           \
    const int _buf = (s)&1;                                                   \
    _Pragma("unroll") for (int _j = 0; _j < 4; ++_j) {                        \
      const int _seg = w * 4 + _j;                                            \
      const int _d = 2 * (s) + (_seg >> 4);                                   \
      const int _key = (_seg & 15) * 128 + lane * 2;                          \
      __builtin_amdgcn_global_load_lds(GAS(Kbh + (size_t)_d * NN + _key),     \
                                       LAS(KS + _buf * 4096 + _seg * 128 +    \
                                           lane * 2),                         \
                                       16, 0, 0);                             \
    }                                                                         \
  }

  ISSUE_STAGE(0);
  __syncthreads();  // Qrow visible + stage 0 landed (syncthreads drains vmcnt)

  // ---- QK^T: acc[r][j] = S[n0+r][256w + lane + 64j], fp64, d-ascending ----
  double acc[8][4];
#pragma unroll
  for (int r = 0; r < 8; ++r)
#pragma unroll
    for (int j = 0; j < 4; ++j) acc[r][j] = 0.0;

#pragma unroll 1
  for (int s = 0; s < 32; ++s) {
    if (s + 1 < 32) {
      ISSUE_STAGE(s + 1);
      asm volatile("s_waitcnt vmcnt(4)" ::: "memory");
    } else {
      asm volatile("s_waitcnt vmcnt(0)" ::: "memory");
    }
    __builtin_amdgcn_s_barrier();  // stage s visible to all waves

    const double* Kb = KS + (s & 1) * 4096;
#pragma unroll
    for (int dl = 0; dl < 2; ++dl) {
      const int d = 2 * s + dl;
      double q[8];
#pragma unroll
      for (int r = 0; r < 8; ++r) q[r] = Qrow[r][d];
      double kv[4];
#pragma unroll
      for (int j = 0; j < 4; ++j) kv[j] = Kb[dl * 2048 + w * 256 + lane + 64 * j];
#pragma unroll
      for (int r = 0; r < 8; ++r)
#pragma unroll
        for (int j = 0; j < 4; ++j) acc[r][j] = fma(q[r], kv[j], acc[r][j]);
    }
    asm volatile("s_waitcnt lgkmcnt(0)" ::: "memory");
    __builtin_amdgcn_s_barrier();  // reads done before buf reuse
  }

  // ---- transpose scores (2 halves of 4 rows) + R4-verified selection ----
#pragma unroll 1
  for (int h = 0; h < 2; ++h) {
#pragma unroll
    for (int lr = 0; lr < 4; ++lr)
#pragma unroll
      for (int j = 0; j < 4; ++j)
        KS[lr * 2048 + w * 256 + lane + 64 * j] = acc[4 * h + lr][j];
    __syncthreads();

    if ((w >> 2) == h) {
      const int lr = w & 3;
      double sv[32];
#pragma unroll
      for (int i = 0; i < 32; ++i) sv[i] = KS[lr * 2048 + lane + 64 * i];

      // row max (fp64)
      double mxd = sv[0];
#pragma unroll
      for (int i = 1; i < 32; ++i) mxd = fmax(mxd, sv[i]);
#pragma unroll
      for (int m = 1; m < 64; m <<= 1) mxd = fmax(mxd, __shfl_xor(mxd, m, 64));

      // monotone u32 keys from fp32 casts
      unsigned ka[32];
#pragma unroll
      for (int i = 0; i < 32; ++i) {
        const int ib = __float_as_int((float)sv[i]);
        ka[i] = (unsigned)ib ^ ((ib < 0) ? 0xFFFFFFFFu : 0x80000000u);
      }

      // binary search: largest T32 with count(ka >= T32) >= 204
      unsigned T32 = 0;
#pragma unroll 1
      for (int bit = 31; bit >= 0; --bit) {
        const unsigned cand = T32 | (1u << bit);
        int c = 0;
#pragma unroll
        for (int i = 0; i < 32; ++i) c += (ka[i] >= cand) ? 1 : 0;
#pragma unroll
        for (int m = 1; m < 64; m <<= 1) c += __shfl_xor(c, m, 64);
        if (c >= KSP) T32 = cand;
      }

      // exact-tie accounting
      int cpk = 0;
#pragma unroll
      for (int i = 0; i < 32; ++i)
        cpk += (ka[i] > T32) ? (1 << 12) : ((ka[i] == T32) ? 1 : 0);
#pragma unroll
      for (int m = 1; m < 64; m <<= 1) cpk += __shfl_xor(cpk, m, 64);
      const int cgt = cpk >> 12, ceq = cpk & 0xFFF;

      unsigned selmask = 0;
      if (cgt + ceq == KSP) {
#pragma unroll
        for (int i = 0; i < 32; ++i) selmask |= (ka[i] >= T32) ? (1u << i) : 0u;
      } else {  // rare: resolve with exact fp64 keys
        unsigned long long T = 0ull;
#pragma unroll 1
        for (int bit = 63; bit >= 0; --bit) {
          const unsigned long long cand = T | (1ull << bit);
          int c = 0;
#pragma unroll
          for (int i = 0; i < 32; ++i)
            c += (ka[i] == T32 && mono64(sv[i]) >= cand) ? 1 : 0;
#pragma unroll
          for (int m = 1; m < 64; m <<= 1) c += __shfl_xor(c, m, 64);
          if (cgt + c >= KSP) T = cand;
        }
#pragma unroll
        for (int i = 0; i < 32; ++i)
          selmask |= ((ka[i] > T32) || (ka[i] == T32 && mono64(sv[i]) >= T))
                         ? (1u << i)
                         : 0u;
      }

      // softmax numerators (f16) + Z
      float z = 0.f;
#pragma unroll
      for (int i = 0; i < 32; ++i) {
        const float p =
            ((selmask >> i) & 1u) ? __expf((float)(sv[i] - mxd)) : 0.0f;
        Pf[w][lane + 64 * i] = (_Float16)p;
        z += p;
      }
#pragma unroll
      for (int m = 1; m < 64; m <<= 1) z += __shfl_xor(z, m, 64);
      if (lane == 0) Zrow[w] = z;
    }
    __syncthreads();
  }

  // ---- PV: wave w owns d in [w*8, w*8+8) (R4 verbatim) ----
  const int b2 = bh >> 4, h2 = bh & 15;
#pragma unroll 1
  for (int dd = 0; dd < 8; ++dd) {
    const int d = w * 8 + dd;
    const float* vr = Vf + ((size_t)bh * HD + d) * NN + lane;
    float vv[32];
#pragma unroll
    for (int i = 0; i < 32; ++i) vv[i] = vr[i * 64];
#pragma unroll 1
    for (int r2 = 0; r2 < 8; ++r2) {
      float s = 0.f;
#pragma unroll
      for (int i = 0; i < 32; ++i)
        s = fmaf((float)Pf[r2][lane + 64 * i], vv[i], s);
#pragma unroll
      for (int m = 1; m < 64; m <<= 1) s += __shfl_xor(s, m, 64);
      if (lane == 0)
        attnv[((size_t)(b2 * NN + n0 + r2)) * CC + h2 * HD + d] = s / Zrow[r2];
    }
  }
}

// ---------------------------------------------------------------------------
// Kernel 3: out = attnv @ w_out + b_out, fp32, 64x64 tile, 4x4 micro. (R4)
// ---------------------------------------------------------------------------
__global__ __launch_bounds__(256) void out_gemm_f32(
    const float* __restrict__ A, const float* __restrict__ W,
    const float* __restrict__ bout, float* __restrict__ out) {
  __shared__ float As[16][64];
  __shared__ float Bs[16][64];
  const int tid = threadIdx.x;
  const int tx = tid & 15, ty = tid >> 4;
  const int colbase = blockIdx.x * 64, rowbase = blockIdx.y * 64;

  float acc[4][4] = {};

  const int sr = tid >> 2, sc = (tid & 3) * 4;
  const int bk = tid >> 4, bn = (tid & 15) * 4;

  for (int kt = 0; kt < 64; ++kt) {
    const int k0 = kt * 16;
    const float4 av = *(const float4*)(A + (size_t)(rowbase + sr) * 1024 + k0 + sc);
    const float4 bv = *(const float4*)(W + (size_t)(k0 + bk) * 1024 + colbase + bn);
    __syncthreads();
    As[sc + 0][sr] = av.x;
    As[sc + 1][sr] = av.y;
    As[sc + 2][sr] = av.z;
    As[sc + 3][sr] = av.w;
    Bs[bk][bn + 0] = bv.x;
    Bs[bk][bn + 1] = bv.y;
    Bs[bk][bn + 2] = bv.z;
    Bs[bk][bn + 3] = bv.w;
    __syncthreads();
#pragma unroll
    for (int k = 0; k < 16; ++k) {
      float a[4], b[4];
#pragma unroll
      for (int i = 0; i < 4; ++i) a[i] = As[k][ty + 16 * i];
#pragma unroll
      for (int j = 0; j < 4; ++j) b[j] = Bs[k][tx + 16 * j];
#pragma unroll
      for (int i = 0; i < 4; ++i)
#pragma unroll
        for (int j = 0; j < 4; ++j) acc[i][j] = fmaf(a[i], b[j], acc[i][j]);
    }
  }

#pragma unroll
  for (int j = 0; j < 4; ++j) {
    const int col = colbase + tx + 16 * j;
    const float bias = bout[col];
#pragma unroll
    for (int i = 0; i < 4; ++i) {
      const int row = rowbase + ty + 16 * i;
      out[(size_t)row * CC + col] = acc[i][j] + bias;
    }
  }
}

// ---------------------------------------------------------------------------
extern "C" void kernel_launch(void* const* d_in, const int* in_sizes, int n_in,
                              void* d_out, int out_size, void* d_ws,
                              size_t ws_size, hipStream_t stream) {
  const float* x     = (const float*)d_in[0];
  const float* w_qkv = (const float*)d_in[1];
  const float* b_qkv = (const float*)d_in[2];
  const float* w_out = (const float*)d_in[3];
  const float* b_out = (const float*)d_in[4];
  float* out = (float*)d_out;

  char* ws = (char*)d_ws;
  const size_t SZ_QD = (size_t)BB * HH * HD * NN * 8;  // 33.55 MB
  const size_t SZ_VF = (size_t)BB * HH * HD * NN * 4;  // 16.78 MB
  const size_t SZ_AT = (size_t)4096 * 1024 * 4;        // 16.78 MB

  size_t off = 0;
  double* Qd    = (double*)(ws + off); off += SZ_QD;
  double* Kd    = (double*)(ws + off); off += SZ_QD;
  float*  Vf    = (float*)(ws + off);  off += SZ_VF;
  float*  attnv = (float*)(ws + off);  off += SZ_AT;

  {
    dim3 g(3072 / 64, 4096 / 64);
    qkv_gemm_f64<<<g, 256, 0, stream>>>(x, w_qkv, b_qkv, Qd, Kd, Vf);
  }
  attn_exact<<<BB * HH * (NN / 8), 512, 0, stream>>>(Qd, Kd, Vf, attnv);
  {
    dim3 g(1024 / 64, 4096 / 64);
    out_gemm_f32<<<g, 256, 0, stream>>>(attnv, w_out, b_out, out);
  }
}

// Round 6
// 4106.311 us; speedup vs baseline: 1.0748x; 1.0748x over previous
//
#include <hip/hip_runtime.h>
#include <cstdint>

// ---------------------------------------------------------------------------
// SparseAttention — R6: fix the R5 scratch-spill (runtime-indexed acc ->
// localMem, rule #20). Transpose halves are now statically indexed via a
// literal-constant macro + forceinline selection fn. Added XCD-chunked block
// swizzle in attn; split V projection into an fp32 kernel (Q,K stay fp64).
// Selection semantics bit-identical to R3/R4/R5 (absmax must stay 2.563e-3).
// ---------------------------------------------------------------------------

#define BB 2
#define NN 2048
#define CC 1024
#define HH 16
#define HD 64
#define KSP 204

#define LAS(p) ((__attribute__((address_space(3))) void*)(uintptr_t)(p))
#define GAS(p) ((const __attribute__((address_space(1))) void*)(uintptr_t)(p))

__device__ __forceinline__ unsigned long long mono64(double s) {
  long long bb = __double_as_longlong(s);
  return (unsigned long long)bb ^
         ((bb < 0) ? 0xFFFFFFFFFFFFFFFFull : 0x8000000000000000ull);
}

// ---------------------------------------------------------------------------
// Kernel 1: Q,K projection in fp64. 64x64 tile, 4x4 micro. Cols [0,2048).
// ---------------------------------------------------------------------------
__global__ __launch_bounds__(256) void qk_gemm_f64(
    const float* __restrict__ x, const float* __restrict__ w,
    const float* __restrict__ bqkv, double* __restrict__ Qd,
    double* __restrict__ Kd) {
  __shared__ double As[16][64];  // [k][m]
  __shared__ double Bs[16][64];  // [k][n]
  const int tid = threadIdx.x;
  const int tx = tid & 15, ty = tid >> 4;
  const int colbase = blockIdx.x * 64, rowbase = blockIdx.y * 64;

  double acc[4][4] = {};

  const int sr = tid >> 2, sc = (tid & 3) * 4;
  const int bk = tid >> 4, bn = (tid & 15) * 4;

  for (int kt = 0; kt < 64; ++kt) {
    const int k0 = kt * 16;
    const float4 av = *(const float4*)(x + (size_t)(rowbase + sr) * 1024 + k0 + sc);
    const float4 bv = *(const float4*)(w + (size_t)(k0 + bk) * 3072 + colbase + bn);
    __syncthreads();
    As[sc + 0][sr] = (double)av.x;
    As[sc + 1][sr] = (double)av.y;
    As[sc + 2][sr] = (double)av.z;
    As[sc + 3][sr] = (double)av.w;
    Bs[bk][bn + 0] = (double)bv.x;
    Bs[bk][bn + 1] = (double)bv.y;
    Bs[bk][bn + 2] = (double)bv.z;
    Bs[bk][bn + 3] = (double)bv.w;
    __syncthreads();
#pragma unroll
    for (int k = 0; k < 16; ++k) {
      double a[4], b[4];
#pragma unroll
      for (int i = 0; i < 4; ++i) a[i] = As[k][ty + 16 * i];
#pragma unroll
      for (int j = 0; j < 4; ++j) b[j] = Bs[k][tx + 16 * j];
#pragma unroll
      for (int i = 0; i < 4; ++i)
#pragma unroll
        for (int j = 0; j < 4; ++j) acc[i][j] = fma(a[i], b[j], acc[i][j]);
    }
  }

  const int region = colbase >> 10;  // 0=Q 1=K (uniform per block)
#pragma unroll
  for (int j = 0; j < 4; ++j) {
    const int col = colbase + tx + 16 * j;
    const double bias = (double)bqkv[col];
    const int h = (col & 1023) >> 6, d = col & 63;
#pragma unroll
    for (int i = 0; i < 4; ++i) {
      const int row = rowbase + ty + 16 * i;
      const int b = row >> 11, n = row & 2047;
      const size_t o = ((size_t)((b * HH + h) * HD + d)) * NN + n;
      const double v = acc[i][j] + bias;
      if (region == 0)
        Qd[o] = v * 0.125;
      else
        Kd[o] = v;
    }
  }
}

// ---------------------------------------------------------------------------
// Kernel 1b: V projection in fp32. Cols [2048,3072) of w_qkv.
// ---------------------------------------------------------------------------
__global__ __launch_bounds__(256) void v_gemm_f32(
    const float* __restrict__ x, const float* __restrict__ w,
    const float* __restrict__ bqkv, float* __restrict__ Vf) {
  __shared__ float As[16][64];
  __shared__ float Bs[16][64];
  const int tid = threadIdx.x;
  const int tx = tid & 15, ty = tid >> 4;
  const int colbase = blockIdx.x * 64, rowbase = blockIdx.y * 64;

  float acc[4][4] = {};

  const int sr = tid >> 2, sc = (tid & 3) * 4;
  const int bk = tid >> 4, bn = (tid & 15) * 4;

  for (int kt = 0; kt < 64; ++kt) {
    const int k0 = kt * 16;
    const float4 av = *(const float4*)(x + (size_t)(rowbase + sr) * 1024 + k0 + sc);
    const float4 bv =
        *(const float4*)(w + (size_t)(k0 + bk) * 3072 + 2048 + colbase + bn);
    __syncthreads();
    As[sc + 0][sr] = av.x;
    As[sc + 1][sr] = av.y;
    As[sc + 2][sr] = av.z;
    As[sc + 3][sr] = av.w;
    Bs[bk][bn + 0] = bv.x;
    Bs[bk][bn + 1] = bv.y;
    Bs[bk][bn + 2] = bv.z;
    Bs[bk][bn + 3] = bv.w;
    __syncthreads();
#pragma unroll
    for (int k = 0; k < 16; ++k) {
      float a[4], b[4];
#pragma unroll
      for (int i = 0; i < 4; ++i) a[i] = As[k][ty + 16 * i];
#pragma unroll
      for (int j = 0; j < 4; ++j) b[j] = Bs[k][tx + 16 * j];
#pragma unroll
      for (int i = 0; i < 4; ++i)
#pragma unroll
        for (int j = 0; j < 4; ++j) acc[i][j] = fmaf(a[i], b[j], acc[i][j]);
    }
  }

#pragma unroll
  for (int j = 0; j < 4; ++j) {
    const int col = colbase + tx + 16 * j;
    const float bias = bqkv[2048 + col];
    const int h = col >> 6, d = col & 63;
#pragma unroll
    for (int i = 0; i < 4; ++i) {
      const int row = rowbase + ty + 16 * i;
      const int b = row >> 11, n = row & 2047;
      Vf[((size_t)((b * HH + h) * HD + d)) * NN + n] = acc[i][j] + bias;
    }
  }
}

// ---------------------------------------------------------------------------
// Selection + softmax for one q-row (R4-verified, verbatim semantics).
// S = 2048 fp64 scores in LDS; writes 2048 f16 numerators + Z.
// ---------------------------------------------------------------------------
__device__ __forceinline__ void do_select(const double* __restrict__ S,
                                          _Float16* __restrict__ Prow,
                                          float* __restrict__ Zout, int lane) {
  double sv[32];
#pragma unroll
  for (int i = 0; i < 32; ++i) sv[i] = S[lane + 64 * i];

  // row max (fp64)
  double mxd = sv[0];
#pragma unroll
  for (int i = 1; i < 32; ++i) mxd = fmax(mxd, sv[i]);
#pragma unroll
  for (int m = 1; m < 64; m <<= 1) mxd = fmax(mxd, __shfl_xor(mxd, m, 64));

  // monotone u32 keys from fp32 casts
  unsigned ka[32];
#pragma unroll
  for (int i = 0; i < 32; ++i) {
    const int ib = __float_as_int((float)sv[i]);
    ka[i] = (unsigned)ib ^ ((ib < 0) ? 0xFFFFFFFFu : 0x80000000u);
  }

  // binary search: largest T32 with count(ka >= T32) >= 204
  unsigned T32 = 0;
#pragma unroll 1
  for (int bit = 31; bit >= 0; --bit) {
    const unsigned cand = T32 | (1u << bit);
    int c = 0;
#pragma unroll
    for (int i = 0; i < 32; ++i) c += (ka[i] >= cand) ? 1 : 0;
#pragma unroll
    for (int m = 1; m < 64; m <<= 1) c += __shfl_xor(c, m, 64);
    if (c >= KSP) T32 = cand;
  }

  // exact-tie accounting
  int cpk = 0;
#pragma unroll
  for (int i = 0; i < 32; ++i)
    cpk += (ka[i] > T32) ? (1 << 12) : ((ka[i] == T32) ? 1 : 0);
#pragma unroll
  for (int m = 1; m < 64; m <<= 1) cpk += __shfl_xor(cpk, m, 64);
  const int cgt = cpk >> 12, ceq = cpk & 0xFFF;

  unsigned selmask = 0;
  if (cgt + ceq == KSP) {
#pragma unroll
    for (int i = 0; i < 32; ++i) selmask |= (ka[i] >= T32) ? (1u << i) : 0u;
  } else {  // rare: resolve with exact fp64 keys
    unsigned long long T = 0ull;
#pragma unroll 1
    for (int bit = 63; bit >= 0; --bit) {
      const unsigned long long cand = T | (1ull << bit);
      int c = 0;
#pragma unroll
      for (int i = 0; i < 32; ++i)
        c += (ka[i] == T32 && mono64(sv[i]) >= cand) ? 1 : 0;
#pragma unroll
      for (int m = 1; m < 64; m <<= 1) c += __shfl_xor(c, m, 64);
      if (cgt + c >= KSP) T = cand;
    }
#pragma unroll
    for (int i = 0; i < 32; ++i)
      selmask |= ((ka[i] > T32) || (ka[i] == T32 && mono64(sv[i]) >= T))
                     ? (1u << i)
                     : 0u;
  }

  // softmax numerators (f16) + Z
  float z = 0.f;
#pragma unroll
  for (int i = 0; i < 32; ++i) {
    const float p = ((selmask >> i) & 1u) ? __expf((float)(sv[i] - mxd)) : 0.0f;
    Prow[lane + 64 * i] = (_Float16)p;
    z += p;
  }
#pragma unroll
  for (int m = 1; m < 64; m <<= 1) z += __shfl_xor(z, m, 64);
  if (lane == 0) *Zout = z;
}

// ---------------------------------------------------------------------------
// Kernel 2: fused sparse attention (R5 structure, spill-free transpose).
// ---------------------------------------------------------------------------
__global__ __launch_bounds__(512) void attn_exact(
    const double* __restrict__ Qd, const double* __restrict__ Kd,
    const float* __restrict__ Vf, float* __restrict__ attnv) {
  __shared__ double KS[8192];       // 64KB: K dbuf / score-transpose scratch
  __shared__ _Float16 Pf[8][2048];  // 32KB
  __shared__ double Qrow[8][64];    // 4KB
  __shared__ float Zrow[8];

  const int tid = threadIdx.x;
  const int lane = tid & 63;
  const int w = tid >> 6;

  // XCD-chunked swizzle (bijective, 8192 % 8 == 0): each XCD runs 1024
  // consecutive logical blocks = 4 bh-groups -> K panel stays L2-resident.
  const int bid = (int)(blockIdx.x & 7) * 1024 + ((int)blockIdx.x >> 3);
  const int bh = bid >> 8;
  const int n0 = (bid & 255) * 8;

  Qrow[w][lane] = Qd[((size_t)bh * HD + lane) * NN + n0 + w];

  const double* Kbh = Kd + (size_t)bh * HD * NN;

  // stage s covers d-rows {2s, 2s+1}; 32 segments of 1024B; wave w does 4.
#define ISSUE_STAGE(s)                                                        \
  {                                                                           \
    const int _buf = (s)&1;                                                   \
    _Pragma("unroll") for (int _j = 0; _j < 4; ++_j) {                        \
      const int _seg = w * 4 + _j;                                            \
      const int _d = 2 * (s) + (_seg >> 4);                                   \
      const int _key = (_seg & 15) * 128 + lane * 2;                          \
      __builtin_amdgcn_global_load_lds(GAS(Kbh + (size_t)_d * NN + _key),     \
                                       LAS(KS + _buf * 4096 + _seg * 128 +    \
                                           lane * 2),                         \
                                       16, 0, 0);                             \
    }                                                                         \
  }

  ISSUE_STAGE(0);
  __syncthreads();  // Qrow visible + stage 0 landed

  // ---- QK^T: acc[r][j] = S[n0+r][256w + lane + 64j], fp64, d-ascending ----
  double acc[8][4];
#pragma unroll
  for (int r = 0; r < 8; ++r)
#pragma unroll
    for (int j = 0; j < 4; ++j) acc[r][j] = 0.0;

#pragma unroll 1
  for (int s = 0; s < 32; ++s) {
    if (s + 1 < 32) {
      ISSUE_STAGE(s + 1);
      asm volatile("s_waitcnt vmcnt(4)" ::: "memory");
    } else {
      asm volatile("s_waitcnt vmcnt(0)" ::: "memory");
    }
    __builtin_amdgcn_s_barrier();  // stage s visible to all waves

    const double* Kb = KS + (s & 1) * 4096;
#pragma unroll
    for (int dl = 0; dl < 2; ++dl) {
      const int d = 2 * s + dl;
      double q[8];
#pragma unroll
      for (int r = 0; r < 8; ++r) q[r] = Qrow[r][d];
      double kv[4];
#pragma unroll
      for (int j = 0; j < 4; ++j)
        kv[j] = Kb[dl * 2048 + w * 256 + lane + 64 * j];
#pragma unroll
      for (int r = 0; r < 8; ++r)
#pragma unroll
        for (int j = 0; j < 4; ++j) acc[r][j] = fma(q[r], kv[j], acc[r][j]);
    }
    asm volatile("s_waitcnt lgkmcnt(0)" ::: "memory");
    __builtin_amdgcn_s_barrier();  // reads done before buf reuse
  }

  // ---- transpose halves (LITERAL h -> acc stays in registers) ----
#define TRANS_HALF(hh)                                                       \
  {                                                                          \
    _Pragma("unroll") for (int lr = 0; lr < 4; ++lr)                         \
        _Pragma("unroll") for (int j = 0; j < 4; ++j)                        \
            KS[lr * 2048 + w * 256 + lane + 64 * j] = acc[4 * (hh) + lr][j]; \
    __syncthreads();                                                         \
    if ((w >> 2) == (hh))                                                    \
      do_select(&KS[(w & 3) * 2048], &Pf[w][0], &Zrow[w], lane);             \
    __syncthreads();                                                         \
  }

  TRANS_HALF(0)
  TRANS_HALF(1)

  // ---- PV: wave w owns d in [w*8, w*8+8) ----
  const int b2 = bh >> 4, h2 = bh & 15;
#pragma unroll 1
  for (int dd = 0; dd < 8; ++dd) {
    const int d = w * 8 + dd;
    const float* vr = Vf + ((size_t)bh * HD + d) * NN + lane;
    float vv[32];
#pragma unroll
    for (int i = 0; i < 32; ++i) vv[i] = vr[i * 64];
#pragma unroll 1
    for (int r2 = 0; r2 < 8; ++r2) {
      float s = 0.f;
#pragma unroll
      for (int i = 0; i < 32; ++i)
        s = fmaf((float)Pf[r2][lane + 64 * i], vv[i], s);
#pragma unroll
      for (int m = 1; m < 64; m <<= 1) s += __shfl_xor(s, m, 64);
      if (lane == 0)
        attnv[((size_t)(b2 * NN + n0 + r2)) * CC + h2 * HD + d] = s / Zrow[r2];
    }
  }
}

// ---------------------------------------------------------------------------
// Kernel 3: out = attnv @ w_out + b_out, fp32, 64x64 tile, 4x4 micro.
// ---------------------------------------------------------------------------
__global__ __launch_bounds__(256) void out_gemm_f32(
    const float* __restrict__ A, const float* __restrict__ W,
    const float* __restrict__ bout, float* __restrict__ out) {
  __shared__ float As[16][64];
  __shared__ float Bs[16][64];
  const int tid = threadIdx.x;
  const int tx = tid & 15, ty = tid >> 4;
  const int colbase = blockIdx.x * 64, rowbase = blockIdx.y * 64;

  float acc[4][4] = {};

  const int sr = tid >> 2, sc = (tid & 3) * 4;
  const int bk = tid >> 4, bn = (tid & 15) * 4;

  for (int kt = 0; kt < 64; ++kt) {
    const int k0 = kt * 16;
    const float4 av = *(const float4*)(A + (size_t)(rowbase + sr) * 1024 + k0 + sc);
    const float4 bv = *(const float4*)(W + (size_t)(k0 + bk) * 1024 + colbase + bn);
    __syncthreads();
    As[sc + 0][sr] = av.x;
    As[sc + 1][sr] = av.y;
    As[sc + 2][sr] = av.z;
    As[sc + 3][sr] = av.w;
    Bs[bk][bn + 0] = bv.x;
    Bs[bk][bn + 1] = bv.y;
    Bs[bk][bn + 2] = bv.z;
    Bs[bk][bn + 3] = bv.w;
    __syncthreads();
#pragma unroll
    for (int k = 0; k < 16; ++k) {
      float a[4], b[4];
#pragma unroll
      for (int i = 0; i < 4; ++i) a[i] = As[k][ty + 16 * i];
#pragma unroll
      for (int j = 0; j < 4; ++j) b[j] = Bs[k][tx + 16 * j];
#pragma unroll
      for (int i = 0; i < 4; ++i)
#pragma unroll
        for (int j = 0; j < 4; ++j) acc[i][j] = fmaf(a[i], b[j], acc[i][j]);
    }
  }

#pragma unroll
  for (int j = 0; j < 4; ++j) {
    const int col = colbase + tx + 16 * j;
    const float bias = bout[col];
#pragma unroll
    for (int i = 0; i < 4; ++i) {
      const int row = rowbase + ty + 16 * i;
      out[(size_t)row * CC + col] = acc[i][j] + bias;
    }
  }
}

// ---------------------------------------------------------------------------
extern "C" void kernel_launch(void* const* d_in, const int* in_sizes, int n_in,
                              void* d_out, int out_size, void* d_ws,
                              size_t ws_size, hipStream_t stream) {
  const float* x     = (const float*)d_in[0];
  const float* w_qkv = (const float*)d_in[1];
  const float* b_qkv = (const float*)d_in[2];
  const float* w_out = (const float*)d_in[3];
  const float* b_out = (const float*)d_in[4];
  float* out = (float*)d_out;

  char* ws = (char*)d_ws;
  const size_t SZ_QD = (size_t)BB * HH * HD * NN * 8;  // 33.55 MB
  const size_t SZ_VF = (size_t)BB * HH * HD * NN * 4;  // 16.78 MB
  const size_t SZ_AT = (size_t)4096 * 1024 * 4;        // 16.78 MB

  size_t off = 0;
  double* Qd    = (double*)(ws + off); off += SZ_QD;
  double* Kd    = (double*)(ws + off); off += SZ_QD;
  float*  Vf    = (float*)(ws + off);  off += SZ_VF;
  float*  attnv = (float*)(ws + off);  off += SZ_AT;

  {
    dim3 g(2048 / 64, 4096 / 64);
    qk_gemm_f64<<<g, 256, 0, stream>>>(x, w_qkv, b_qkv, Qd, Kd);
  }
  {
    dim3 g(1024 / 64, 4096 / 64);
    v_gemm_f32<<<g, 256, 0, stream>>>(x, w_qkv, b_qkv, Vf);
  }
  attn_exact<<<BB * HH * (NN / 8), 512, 0, stream>>>(Qd, Kd, Vf, attnv);
  {
    dim3 g(1024 / 64, 4096 / 64);
    out_gemm_f32<<<g, 256, 0, stream>>>(attnv, w_out, b_out, out);
  }
}